// Round 8
// baseline (286.904 us; speedup 1.0000x reference)
//
#include <hip/hip_runtime.h>
#include <hip/hip_bf16.h>

#define NN 100000
#define EE 1000000
#define H_DIM 124
#define PCOLS 512
#define LDK 136   // 128 + 8 bf16 pad
#define CW 132    // f32 staging stride in dwords

typedef float f32x4 __attribute__((ext_vector_type(4)));
typedef short bf16x8 __attribute__((ext_vector_type(8)));
typedef _Float16 h2 __attribute__((ext_vector_type(2)));

__device__ __forceinline__ unsigned short f2bf(float f) {
    unsigned int x = __float_as_uint(f);
    unsigned int r = (x + 0x7FFFu + ((x >> 16) & 1u)) >> 16;
    return (unsigned short)r;
}
__device__ __forceinline__ unsigned int pk2bf(float a, float b) {
    return (unsigned int)f2bf(a) | ((unsigned int)f2bf(b) << 16);
}
__device__ __forceinline__ unsigned int pk2h(float a, float b) {
    h2 v = (h2){(_Float16)a, (_Float16)b};
    return __builtin_bit_cast(unsigned int, v);
}

__device__ __forceinline__ float fdot2(h2 a, h2 b, float c) {
#if __has_builtin(__builtin_amdgcn_fdot2)
    return __builtin_amdgcn_fdot2(a, b, c, false);
#else
    return c + (float)a[0] * (float)b[0] + (float)a[1] * (float)b[1];
#endif
}

#if __has_builtin(__builtin_amdgcn_update_dpp)
template <int CTRL>
__device__ __forceinline__ float dpp_add(float x) {
    int xi = __builtin_bit_cast(int, x);
    int t = __builtin_amdgcn_update_dpp(xi, xi, CTRL, 0xF, 0xF, false);
    return x + __builtin_bit_cast(float, t);
}
__device__ __forceinline__ float reduce16(float x) {
    x = dpp_add<0x128>(x);   // row_ror:8
    x = dpp_add<0x124>(x);   // row_ror:4
    x = dpp_add<0x122>(x);   // row_ror:2
    x = dpp_add<0x121>(x);   // row_ror:1
    return x;
}
#else
__device__ __forceinline__ float reduce16(float x) {
    x += __shfl_xor(x, 8); x += __shfl_xor(x, 4);
    x += __shfl_xor(x, 2); x += __shfl_xor(x, 1);
    return x;
}
#endif

__device__ __forceinline__ int bperm(int byte_idx, int v) {
    return __builtin_amdgcn_ds_bpermute(byte_idx, v);
}
__device__ __forceinline__ float bpermf(int byte_idx, float v) {
    return __builtin_bit_cast(float,
        __builtin_amdgcn_ds_bpermute(byte_idx, __builtin_bit_cast(int, v)));
}

struct alignas(16) H8 { h2 p[4]; };

// ---------------- Kernel 1: W1T (bf16 [512,128]) + packed constant table ----------------
__global__ __launch_bounds__(256) void build_w1t_ct(const float* __restrict__ W1,
                                                    const float* __restrict__ gamma,
                                                    const float* __restrict__ beta,
                                                    const float* __restrict__ W2,
                                                    unsigned short* __restrict__ W1T,
                                                    uint4* __restrict__ CT) {
    if (blockIdx.x < 256) {
        int t2 = blockIdx.x * 256 + threadIdx.x;     // 0 .. 65535
        int j = t2 >> 7, k = t2 & 127;
        int row = (j < 256) ? k : (130 + k);
        int col = (j < 256) ? j : (j - 256);
        W1T[t2] = f2bf(W1[row * 256 + col]);
    } else {
        int t = threadIdx.x;
        if (t < 192) {
            int slot = t % 12, il = t / 12;
            int a = slot >> 1, k = slot & 1;
            int j0 = il * 16 + k * 8;
            float v[8];
            #pragma unroll
            for (int i = 0; i < 8; ++i) {
                int j = j0 + i;
                v[i] = (a == 0) ? W1[128 * 256 + j]
                     : (a == 1) ? W1[129 * 256 + j]
                     : (a == 2) ? gamma[j]
                     : (a == 3) ? beta[j]
                     : (a == 4) ? W2[2 * j]
                     :            W2[2 * j + 1];
            }
            CT[t] = make_uint4(pk2h(v[0], v[1]), pk2h(v[2], v[3]),
                               pk2h(v[4], v[5]), pk2h(v[6], v[7]));
        }
    }
}

// ---------------- Kernel 2: fused F-build + P = F @ W1cat (+b1 on dst half) -> fp16 ----------------
__global__ __launch_bounds__(256) void p_gemm(const float* __restrict__ h,
                                              const float* __restrict__ cls,
                                              const unsigned short* __restrict__ W1T,
                                              const float* __restrict__ b1,
                                              _Float16* __restrict__ P) {
    __shared__ alignas(16) unsigned short As[64 * LDK];
    __shared__ alignas(16) unsigned short Bs[128 * LDK];
    float* Cs = (float*)&Bs[0];
    const int m0 = blockIdx.x * 64;
    const int t = threadIdx.x;

    #pragma unroll
    for (int it = 0; it < 4; ++it) {
        int chunk = t + it * 256;
        int r = chunk >> 4, c8 = chunk & 15;
        int row = m0 + r;
        unsigned int w0 = 0, w1 = 0, w2 = 0, w3 = 0;
        if (row < NN) {
            if (c8 < 15) {
                const float* hp = h + (size_t)row * H_DIM + c8 * 8;
                float4 v0 = *(const float4*)(hp);
                float4 v1 = *(const float4*)(hp + 4);
                w0 = pk2bf(v0.x, v0.y); w1 = pk2bf(v0.z, v0.w);
                w2 = pk2bf(v1.x, v1.y); w3 = pk2bf(v1.z, v1.w);
            } else {
                float4 v0 = *(const float4*)(h + (size_t)row * H_DIM + 120);
                float4 c = *(const float4*)(cls + (size_t)row * 4);
                float m = fmaxf(fmaxf(c.x, c.y), fmaxf(c.z, c.w));
                float e0 = __expf(c.x - m), e1 = __expf(c.y - m);
                float e2 = __expf(c.z - m), e3 = __expf(c.w - m);
                float inv = 1.0f / (e0 + e1 + e2 + e3);
                w0 = pk2bf(v0.x, v0.y); w1 = pk2bf(v0.z, v0.w);
                w2 = pk2bf(e0 * inv, e1 * inv); w3 = pk2bf(e2 * inv, e3 * inv);
            }
        }
        *(uint4*)(&As[r * LDK + c8 * 8]) = make_uint4(w0, w1, w2, w3);
    }
    __syncthreads();

    const int wave = t >> 6, lane = t & 63;
    const int wm = wave & 1, wn = wave >> 1;
    const int lm = lane & 15, quad = lane >> 4;

    bf16x8 afrag[4][2];
    #pragma unroll
    for (int s = 0; s < 4; ++s) {
        int k0 = s * 32 + quad * 8;
        #pragma unroll
        for (int mt = 0; mt < 2; ++mt)
            afrag[s][mt] = *(const bf16x8*)(&As[(wm * 32 + mt * 16 + lm) * LDK + k0]);
    }

    for (int cchunk = 0; cchunk < 4; ++cchunk) {
        const int n0 = cchunk * 128;
        if (cchunk) __syncthreads();
        #pragma unroll
        for (int it = 0; it < 8; ++it) {
            int chunk = t + it * 256;
            int r = chunk >> 4, c = chunk & 15;
            float4 v = *(const float4*)(W1T + (n0 + r) * 128 + c * 8);
            *(float4*)(&Bs[r * LDK + c * 8]) = v;
        }
        __syncthreads();

        f32x4 acc[2][4];
        #pragma unroll
        for (int mt = 0; mt < 2; ++mt)
            #pragma unroll
            for (int nt = 0; nt < 4; ++nt)
                acc[mt][nt] = (f32x4){0.f, 0.f, 0.f, 0.f};

        #pragma unroll
        for (int s = 0; s < 4; ++s) {
            int k0 = s * 32 + quad * 8;
            bf16x8 b[4];
            #pragma unroll
            for (int nt = 0; nt < 4; ++nt)
                b[nt] = *(const bf16x8*)(&Bs[(wn * 64 + nt * 16 + lm) * LDK + k0]);
            #pragma unroll
            for (int mt = 0; mt < 2; ++mt)
                #pragma unroll
                for (int nt = 0; nt < 4; ++nt)
                    acc[mt][nt] = __builtin_amdgcn_mfma_f32_16x16x32_bf16(afrag[s][mt], b[nt], acc[mt][nt], 0, 0, 0);
        }
        __syncthreads();

        #pragma unroll
        for (int mt = 0; mt < 2; ++mt)
            #pragma unroll
            for (int nt = 0; nt < 4; ++nt) {
                int col = wn * 64 + nt * 16 + lm;
                int rb  = wm * 32 + mt * 16 + quad * 4;
                #pragma unroll
                for (int r = 0; r < 4; ++r)
                    Cs[(rb + r) * CW + col] = acc[mt][nt][r];
            }
        __syncthreads();

        #pragma unroll
        for (int it = 0; it < 4; ++it) {
            int chunk = t + it * 256;
            int r = chunk >> 4, c8 = chunk & 15;
            float4 a = *(const float4*)(Cs + r * CW + c8 * 8);
            float4 b = *(const float4*)(Cs + r * CW + c8 * 8 + 4);
            if (n0 >= 256) {   // dst half: fold b1 (wave-uniform branch)
                int cb = n0 + c8 * 8 - 256;
                float4 ba = *(const float4*)(b1 + cb);
                float4 bb = *(const float4*)(b1 + cb + 4);
                a.x += ba.x; a.y += ba.y; a.z += ba.z; a.w += ba.w;
                b.x += bb.x; b.y += bb.y; b.z += bb.z; b.w += bb.w;
            }
            uint4 o = make_uint4(pk2h(a.x, a.y), pk2h(a.z, a.w),
                                 pk2h(b.x, b.y), pk2h(b.z, b.w));
            int row = m0 + r;
            if (row < NN)
                *(uint4*)(P + (size_t)row * PCOLS + n0 + c8 * 8) = o;
        }
    }
}

// ---------------- Kernel 3: edges — metadata preloaded in-register, bpermute broadcast ----------------
#define K3_BLOCKS 4096
#define K3_WAVES  (K3_BLOCKS * 4)      // 16384
#define K3_STRIDE (K3_WAVES * 4)       // 65536 edges per round
#define K3_ROUNDS 16                   // 16*65536 = 1,048,576 >= EE

__global__ __launch_bounds__(256) void edge_kernel(const _Float16* __restrict__ P,
                                                   const int* __restrict__ src,
                                                   const int* __restrict__ dst,
                                                   const float* __restrict__ polar,
                                                   const uint4* __restrict__ CT,
                                                   const float* __restrict__ b2,
                                                   float* __restrict__ out) {
    const int lane = threadIdx.x & 63;
    const int il   = lane & 15;                  // lane within edge group
    const int g    = lane >> 4;                  // edge group 0..3
    const int wid  = blockIdx.x * 4 + (threadIdx.x >> 6);
    const char* Pb = (const char*)P;

    // ---- Preload ALL 64 edge-metadata slots for this wave: lane l owns
    // round l>>2, group l&3. 4 loads total; per round just 4 ds_bpermute. ----
    int   ms, md;
    float mq0, mq1;
    {
        int slot_e = wid * 4 + (lane & 3) + (lane >> 2) * K3_STRIDE;
        int ec = (slot_e < EE) ? slot_e : 0;
        ms = src[ec]; md = dst[ec];
        float2 q = *(const float2*)(polar + 2 * ec);
        mq0 = q.x; mq1 = q.y;
    }
    const int bpbase = (lane >> 4) << 2;         // group*4 bytes

    // Pre-packed fp16 constants (12 x dwordx4 from 3 KB L1-hot table).
    uint4 cq[12];
    #pragma unroll
    for (int i = 0; i < 12; ++i) cq[i] = CT[il * 12 + i];
    h2 w0c[8], w1c[8], gc[8], bc[8], w2ac[8], w2bc[8];
    {
        const h2* ch = (const h2*)cq;
        #pragma unroll
        for (int p = 0; p < 8; ++p) {
            w0c[p]  = ch[p];      w1c[p]  = ch[8 + p];
            gc[p]   = ch[16 + p]; bc[p]   = ch[24 + p];
            w2ac[p] = ch[32 + p]; w2bc[p] = ch[40 + p];
        }
    }
    const float b20 = b2[0], b21 = b2[1];
    const h2 onep  = (h2){(_Float16)1.0f, (_Float16)1.0f};
    const h2 zerop = (h2){(_Float16)0.0f, (_Float16)0.0f};

    const unsigned boff_s = (unsigned)(il * 32);         // byte offset within src half
    const unsigned boff_d = (unsigned)(512 + il * 32);   // byte offset within dst half

    // depth-3 P pipeline; metadata already in-register so prefetch has no
    // load->load serialization.
    H8 buf[3][4];
    float qp[3][2];

    #define PREFETCH(slot, r)                                                  \
    {                                                                          \
        int ba = bpbase + (r) * 16;                                            \
        int s  = bperm(ba, ms);                                                \
        int d  = bperm(ba, md);                                                \
        qp[slot][0] = bpermf(ba, mq0);                                         \
        qp[slot][1] = bpermf(ba, mq1);                                         \
        unsigned os = (unsigned)s * 1024u + boff_s;                            \
        unsigned od = (unsigned)d * 1024u + boff_d;                            \
        buf[slot][0] = *(const H8*)(Pb + os);                                  \
        buf[slot][1] = *(const H8*)(Pb + os + 16);                             \
        buf[slot][2] = *(const H8*)(Pb + od);                                  \
        buf[slot][3] = *(const H8*)(Pb + od + 16);                             \
    }

    PREFETCH(0, 0)
    PREFETCH(1, 1)
    PREFETCH(2, 2)

    #define EDGE_COMPUTE(Abuf, q0v, q1v, eg)                                   \
    {                                                                          \
        h2 p0 = (h2){(_Float16)(q0v), (_Float16)(q0v)};                        \
        h2 p1 = (h2){(_Float16)(q1v), (_Float16)(q1v)};                        \
        h2 z[8];                                                               \
        float sum = 0.f, ss = 0.f;                                             \
        _Pragma("unroll")                                                      \
        for (int p = 0; p < 8; ++p) {                                          \
            h2 pv = ((p < 4) ? (Abuf)[0].p[p] : (Abuf)[1].p[p - 4])            \
                  + ((p < 4) ? (Abuf)[2].p[p] : (Abuf)[3].p[p - 4]);           \
            h2 c = w0c[p] * p0 + w1c[p] * p1;                                  \
            z[p] = pv + c;                                                     \
            sum = fdot2(z[p], onep, sum);                                      \
            ss  = fdot2(z[p], z[p], ss);                                       \
        }                                                                      \
        sum = reduce16(sum); ss = reduce16(ss);                                \
        float mu   = sum * (1.0f / 256.0f);                                    \
        float var  = ss * (1.0f / 256.0f) - mu * mu;                           \
        float rstd = rsqrtf(var + 1e-5f);                                      \
        float nmur = -mu * rstd;                                               \
        h2 rsh  = (h2){(_Float16)rstd, (_Float16)rstd};                        \
        h2 nmh  = (h2){(_Float16)nmur, (_Float16)nmur};                        \
        float o0 = 0.f, o1 = 0.f;                                              \
        _Pragma("unroll")                                                      \
        for (int p = 0; p < 8; ++p) {                                          \
            h2 tt = z[p] * rsh + nmh;                                          \
            h2 u = tt * gc[p] + bc[p];                                         \
            u = __builtin_elementwise_max(u, zerop);                           \
            o0 = fdot2(u, w2ac[p], o0);                                        \
            o1 = fdot2(u, w2bc[p], o1);                                        \
        }                                                                      \
        o0 = reduce16(o0); o1 = reduce16(o1);                                  \
        if (il == 0 && (eg) < EE)                                              \
            *(float2*)(out + 2 * (eg)) = make_float2(o0 + b20, o1 + b21);      \
    }

    #pragma unroll
    for (int r = 0; r < K3_ROUNDS; ++r) {
        const int br = r % 3;
        EDGE_COMPUTE(buf[br], qp[br][0], qp[br][1], wid * 4 + g + r * K3_STRIDE);
        if (r + 3 < K3_ROUNDS) {
            PREFETCH(br, r + 3)
        }
    }
    #undef EDGE_COMPUTE
    #undef PREFETCH
}

extern "C" void kernel_launch(void* const* d_in, const int* in_sizes, int n_in,
                              void* d_out, int out_size, void* d_ws, size_t ws_size,
                              hipStream_t stream) {
    const float* h     = (const float*)d_in[0];
    const float* cls   = (const float*)d_in[1];
    const float* polar = (const float*)d_in[2];
    const int*   src   = (const int*)d_in[3];
    const int*   dst   = (const int*)d_in[4];
    const float* W1    = (const float*)d_in[5];
    const float* b1    = (const float*)d_in[6];
    const float* gamma = (const float*)d_in[7];
    const float* beta  = (const float*)d_in[8];
    const float* W2    = (const float*)d_in[9];
    const float* b2    = (const float*)d_in[10];
    float* out = (float*)d_out;

    char* ws = (char*)d_ws;
    _Float16*       P   = (_Float16*)ws;                      // N*512*2 = 102,400,000 B
    unsigned short* W1T = (unsigned short*)(ws + 102400000);  // 131,072 B
    uint4*          CT  = (uint4*)(ws + 102531072);           // 3,072 B

    build_w1t_ct<<<257, 256, 0, stream>>>(W1, gamma, beta, W2, W1T, CT);
    p_gemm<<<1563, 256, 0, stream>>>(h, cls, W1T, b1, P);
    edge_kernel<<<K3_BLOCKS, 256, 0, stream>>>(P, src, dst, polar, CT, b2, out);
}